// Round 14
// baseline (57.199 us; speedup 1.0000x reference)
//
#include <hip/hip_runtime.h>
#include <hip/hip_fp16.h>
#include <cstddef>
#include <cstdint>

#define D_IN  4096
#define D_OUT 4096
#define BB    64
#define NBINB 32     // bin blocks = stripes (block-private, no global atomics)
#define TPB   1024
#define PPT   8      // points per bin thread (NBINB*TPB*PPT >= N)
#define CAP   16     // slots per (col,stripe) cell: mean 2, P(Poisson(2)>16)~1e-10
#define NPREP 64     // prep blocks (xB build + out zero)

// ws layout: [bins: D_OUT*NBINB*CAP*8B = 16MB][cellCnt: D_OUT*NBINB*4B = 512KB]
//            [xB: D_IN*BB*4B = 1MB]
// TWO dispatches (R14 hypothesis: ~5-8us graph overhead per dispatch dominated
// R7-R13's totals). Zero global atomics in binning; no counter zeroing at all
// (cellCnt fully overwritten each replay; stale bin entries never read: e<cnt).
// Entry (8B):
//   .x: rowf[0:11] | rint<<12 | f16(wfr)<<16
//   .y: f16(w_this) | f16(w_next)<<16
// rint = row-is-integer, wcr = rint ? 1 : 1-wfr,
// w_this = v*wfc (+ v*wcc if integer col), w_next = v*wcc (0 if integer col).
// xB[row*BB+b] = bf16(x[row][b]) | bf16(x[row+1][b])<<16 (one u32 gather/entry)
// out[c,:] = sum entries keyed c: w_this*term + keyed c-1: w_next*term,
//   term = wfr*x[rowf,:] + wcr*x[rowc,:] (integer row -> 2*x[rowf], matches ref).

__device__ __forceinline__ uint32_t f2bf_rne(float f) {
  uint32_t u = __float_as_uint(f);
  return (u + 0x7fffu + ((u >> 16) & 1u)) >> 16;   // round-to-nearest-even
}

// ---------------------------------------------------------------------------
// K1: blocks 0..31: stripe-private counting-bin (LDS hist -> rank -> store).
//     blocks 32..95: build xB pair table, zero out. Disjoint arrays -> safe.
// ---------------------------------------------------------------------------
__global__ __launch_bounds__(TPB) void binprep_kernel(
    const float2* __restrict__ ind, const float* __restrict__ val,
    const float* __restrict__ x, uint2* __restrict__ bins,
    uint32_t* __restrict__ cellCnt, uint32_t* __restrict__ xB,
    float* __restrict__ out, int n) {
  const int blk = blockIdx.x;
  const int tid = threadIdx.x;

  if (blk >= NBINB) {
    // ---- prep: 4 elems per thread ----
    int base = (blk - NBINB) * (TPB * 4) + tid;
#pragma unroll
    for (int j = 0; j < 4; j++) {
      int i = base + j * TPB;
      if (i < D_IN * BB) {
        out[i] = 0.f;
        float a = x[i];
        float b = (i + BB < D_IN * BB) ? x[i + BB] : 0.f;
        xB[i] = f2bf_rne(a) | (f2bf_rne(b) << 16);
      }
    }
    return;
  }

  // ---- bin: stripe = blk ----
  __shared__ uint32_t lcnt[D_OUT];
  for (int c = tid; c < D_OUT; c += TPB) lcnt[c] = 0u;
  __syncthreads();

  const int base = blk * (TPB * PPT);
  uint32_t exs[PPT], eys[PPT];
  int keys[PPT];

#pragma unroll
  for (int i = 0; i < PPT; i++) {
    int p = base + i * TPB + tid;
    keys[i] = -1;
    if (p < n) {
      float2 rc = ind[p];
      float v = val[p];
      float flr = floorf(rc.x), cer = ceilf(rc.x);
      float flc = floorf(rc.y), cec = ceilf(rc.y);
      // reference weight: prod_k (1 - |corner_k - ind_k|)
      float wfr = 1.0f - (rc.x - flr);
      float wfc = 1.0f - (rc.y - flc);
      float wcc = 1.0f - (cec - rc.y);
      uint32_t rint = ((int)flr == (int)cer) ? 1u : 0u;
      bool cint = ((int)flc == (int)cec);
      float w_this = cint ? v * (wfc + wcc) : v * wfc;
      float w_next = cint ? 0.f : v * wcc;
      exs[i] = (uint32_t)(int)flr | (rint << 12)
             | ((uint32_t)__half_as_ushort(__float2half_rn(wfr)) << 16);
      eys[i] = (uint32_t)__half_as_ushort(__float2half_rn(w_this))
             | ((uint32_t)__half_as_ushort(__float2half_rn(w_next)) << 16);
      keys[i] = (int)flc;
      uint32_t rank = atomicAdd(&lcnt[keys[i]], 1u);   // LDS returning atomic
      if (rank < CAP)
        bins[((size_t)keys[i] * NBINB + blk) * CAP + rank] =
            make_uint2(exs[i], eys[i]);
    }
  }
  __syncthreads();

  // non-atomic full overwrite: no zeroing needed across replays
  for (int c = tid; c < D_OUT; c += TPB) {
    uint32_t k = lcnt[c];
    cellCnt[(size_t)c * NBINB + blk] = k < CAP ? k : CAP;
  }
}

// ---------------------------------------------------------------------------
// K2: one column per wave (4 cols/block), lane = b. 32 cell counts preloaded
// (8 uint4 scalar loads, blk-loop fully unrolled -> register-resident). Cells
// contiguous per col (4KB); exact-count wave-uniform inner loops; one u32
// bf16-pair gather per entry; dual accumulator; 2 out-atomics per wave.
// ---------------------------------------------------------------------------
__global__ __launch_bounds__(256) void accum_kernel(
    const uint32_t* __restrict__ cellCnt, const uint2* __restrict__ bins,
    const uint32_t* __restrict__ xB, float* __restrict__ out) {
  const int lane = threadIdx.x & 63;
  const int wv   = threadIdx.x >> 6;
  const int col  = blockIdx.x * 4 + wv;

  uint4 cntv[NBINB / 4];
  const uint4* cc = (const uint4*)(cellCnt + (size_t)col * NBINB);
#pragma unroll
  for (int j = 0; j < NBINB / 4; j++) cntv[j] = cc[j];

  float acc_t = 0.f, acc_n = 0.f;

#define PROC(Q)                                                           \
  {                                                                       \
    uint32_t ex_ = (Q).x, ey_ = (Q).y;                                    \
    int rowf = (int)(ex_ & 0xfffu);                                       \
    int rint = (int)((ex_ >> 12) & 1u);                                   \
    float wfr = __half2float(__ushort_as_half((ushort)(ex_ >> 16)));      \
    uint32_t pb = xB[(size_t)rowf * BB + lane];                           \
    float xf = __uint_as_float(pb << 16);                                 \
    float xn = __uint_as_float(pb & 0xffff0000u);                         \
    float xc  = rint ? xf : xn;                                           \
    float wcr = rint ? 1.0f : 1.0f - wfr;                                 \
    float w_t = __half2float(__ushort_as_half((ushort)(ey_ & 0xffffu)));  \
    float w_n = __half2float(__ushort_as_half((ushort)(ey_ >> 16)));      \
    float term = fmaf(wfr, xf, wcr * xc);                                 \
    acc_t = fmaf(w_t, term, acc_t);                                       \
    acc_n = fmaf(w_n, term, acc_n);                                       \
  }

  const uint2* __restrict__ colbase = bins + (size_t)col * NBINB * CAP;
#pragma unroll
  for (int j = 0; j < NBINB / 4; j++) {
    uint32_t c4[4] = {cntv[j].x, cntv[j].y, cntv[j].z, cntv[j].w};
#pragma unroll
    for (int q = 0; q < 4; q++) {
      const int blk = j * 4 + q;
      const int cnt = (int)c4[q];
      const uint2* __restrict__ cell = colbase + (size_t)blk * CAP;
      int e = 0;
      for (; e + 4 <= cnt; e += 4) {
        uint2 a0 = cell[e + 0], a1 = cell[e + 1];
        uint2 a2 = cell[e + 2], a3 = cell[e + 3];
        PROC(a0) PROC(a1) PROC(a2) PROC(a3)
      }
      for (; e < cnt; e++) {
        uint2 a = cell[e];
        PROC(a)
      }
    }
  }
#undef PROC

  atomicAdd(&out[(size_t)col * BB + lane], acc_t);
  if (col + 1 < D_OUT) atomicAdd(&out[(size_t)(col + 1) * BB + lane], acc_n);
}

// ---------------------------------------------------------------------------
// Fallback (ws too small / N too big): direct atomic scatter into out (f32).
// ---------------------------------------------------------------------------
__global__ __launch_bounds__(256) void direct_kernel(
    const float2* __restrict__ ind, const float* __restrict__ val,
    const float* __restrict__ x, float* __restrict__ out, int n) {
  int p = blockIdx.x * 4 + (threadIdx.x >> 6);
  if (p >= n) return;
  int lane = threadIdx.x & 63;
  float2 rc = ind[p];
  float v = val[p];
  float flr = floorf(rc.x), cer = ceilf(rc.x);
  float flc = floorf(rc.y), cec = ceilf(rc.y);
  float wfr = 1.0f - (rc.x - flr);
  float wcr = 1.0f - (cer - rc.x);
  float wfc = 1.0f - (rc.y - flc);
  float wcc = 1.0f - (cec - rc.y);
  float xf = x[(size_t)((int)flr) * BB + lane];
  float xc = x[(size_t)((int)cer) * BB + lane];
  float inner = fmaf(wfr, xf, wcr * xc);
  atomicAdd(&out[(size_t)((int)flc) * BB + lane], v * wfc * inner);
  atomicAdd(&out[(size_t)((int)cec) * BB + lane], v * wcc * inner);
}

// ---------------------------------------------------------------------------
extern "C" void kernel_launch(void* const* d_in, const int* in_sizes, int n_in,
                              void* d_out, int out_size, void* d_ws, size_t ws_size,
                              hipStream_t stream) {
  const float2* ind = (const float2*)d_in[0];   // [N,2] f32
  const float*  val = (const float*)d_in[1];    // [N]   f32
  const float*  x   = (const float*)d_in[2];    // [D_IN*B] f32
  float* out = (float*)d_out;                   // [D_OUT*B] f32
  const int N = in_sizes[1];

  const size_t bin_bytes = (size_t)D_OUT * NBINB * CAP * sizeof(uint2);  // 16 MB
  const size_t cc_bytes  = (size_t)D_OUT * NBINB * sizeof(uint32_t);     // 512 KB
  const size_t xb_bytes  = (size_t)D_IN * BB * sizeof(uint32_t);         // 1 MB

  if (N <= NBINB * TPB * PPT && ws_size >= bin_bytes + cc_bytes + xb_bytes) {
    char* w = (char*)d_ws;
    uint2*    bins    = (uint2*)w;      w += bin_bytes;
    uint32_t* cellCnt = (uint32_t*)w;   w += cc_bytes;
    uint32_t* xB      = (uint32_t*)w;

    binprep_kernel<<<NBINB + NPREP, TPB, 0, stream>>>(
        ind, val, x, bins, cellCnt, xB, out, N);
    accum_kernel<<<D_OUT / 4, 256, 0, stream>>>(cellCnt, bins, xB, out);
  } else {
    (void)hipMemsetAsync(out, 0, (size_t)out_size * sizeof(float), stream);
    direct_kernel<<<(N + 3) / 4, 256, 0, stream>>>(ind, val, x, out, N);
  }
}

// Round 15
// 32.584 us; speedup vs baseline: 1.7554x; 1.7554x over previous
//
#include <hip/hip_runtime.h>
#include <hip/hip_fp16.h>
#include <cstddef>
#include <cstdint>

#define D_IN  4096
#define D_OUT 4096
#define BB    64
#define CAP   128    // slots per column: mean 64, sigma 8 -> 8-sigma headroom
#define NBINB 64     // bin blocks (R15: 2x CU parallelism vs R13)
#define TPB   1024   // bin block threads
#define PPT   4      // points per thread (NBINB*TPB*PPT >= N)

// ws layout: [cnt: D_OUT u32 = 16KB][bins: D_OUT*CAP*8B = 4MB][xB: D_IN*BB*4B = 1MB]
// Entry (8B):
//   .x: rowf[0:11] | rint<<12 | f16(wfr)<<16
//   .y: f16(w_this) | f16(w_next)<<16
// rint = row-is-integer, wcr = rint ? 1 : 1-wfr,
// w_this = v*wfc (+ v*wcc if integer col), w_next = v*wcc (0 if integer col).
// xB[row*BB+b] = bf16(x[row][b]) | bf16(x[row+1][b])<<16  (one u32 gather/entry)
// out[c,:] = sum entries keyed c: w_this*term + keyed c-1: w_next*term,
//   term = wfr*x[rowf,:] + wcr*x[rowc,:] (integer row -> 2*x[rowf], matches ref).
// Bin: block-aggregated base claims (one returning atomic per distinct
// (block,col) ~ 166K total), LDS ranks, contiguous per-col entry runs.
// Accum: explicit 3-stage pipeline (entries -> batched gathers -> FMA) with
// next-chunk entry prefetch to keep ~8 gathers in flight (R14 lesson).

__device__ __forceinline__ uint32_t f2bf_rne(float f) {
  uint32_t u = __float_as_uint(f);
  return (u + 0x7fffu + ((u >> 16) & 1u)) >> 16;   // round-to-nearest-even
}

// ---------------------------------------------------------------------------
// K1: zero cnt + out, build xB packed bf16 pair table.
// ---------------------------------------------------------------------------
__global__ __launch_bounds__(256) void prep_kernel(
    const float* __restrict__ x, uint32_t* __restrict__ cnt,
    float* __restrict__ out, uint32_t* __restrict__ xB) {
  int i = blockIdx.x * 256 + threadIdx.x;     // 0 .. D_IN*BB-1
  if (i < D_OUT) cnt[i] = 0u;
  out[i] = 0.f;
  float a = x[i];
  float b = (i + BB < D_IN * BB) ? x[i + BB] : 0.f;
  xB[i] = f2bf_rne(a) | (f2bf_rne(b) << 16);
}

// ---------------------------------------------------------------------------
// K2: block-aggregated counting-bin (64 blocks x 1024 thr x 4 pts).
//  1) decode entries to registers, LDS histogram of keys
//  2) one global returning atomicAdd per DISTINCT (block,col) claims a run
//  3) slot = claimed base + LDS rank -> contiguous per-col entry runs
// ---------------------------------------------------------------------------
__global__ __launch_bounds__(TPB) void bin_kernel(
    const float2* __restrict__ ind, const float* __restrict__ val,
    uint32_t* __restrict__ cnt, uint2* __restrict__ bins, int n) {
  __shared__ uint32_t lcnt[D_OUT];
  __shared__ uint32_t lbase[D_OUT];
  const int tid = threadIdx.x;
  for (int c = tid; c < D_OUT; c += TPB) lcnt[c] = 0u;
  __syncthreads();

  const int base = blockIdx.x * (TPB * PPT);
  uint32_t exs[PPT], eys[PPT];
  int keys[PPT];

#pragma unroll
  for (int i = 0; i < PPT; i++) {
    int p = base + i * TPB + tid;
    keys[i] = -1;
    if (p < n) {
      float2 rc = ind[p];
      float v = val[p];
      float flr = floorf(rc.x), cer = ceilf(rc.x);
      float flc = floorf(rc.y), cec = ceilf(rc.y);
      // reference weight: prod_k (1 - |corner_k - ind_k|)
      float wfr = 1.0f - (rc.x - flr);
      float wfc = 1.0f - (rc.y - flc);
      float wcc = 1.0f - (cec - rc.y);
      uint32_t rint = ((int)flr == (int)cer) ? 1u : 0u;
      bool cint = ((int)flc == (int)cec);
      float w_this = cint ? v * (wfc + wcc) : v * wfc;
      float w_next = cint ? 0.f : v * wcc;
      exs[i] = (uint32_t)(int)flr | (rint << 12)
             | ((uint32_t)__half_as_ushort(__float2half_rn(wfr)) << 16);
      eys[i] = (uint32_t)__half_as_ushort(__float2half_rn(w_this))
             | ((uint32_t)__half_as_ushort(__float2half_rn(w_next)) << 16);
      keys[i] = (int)flc;
      atomicAdd(&lcnt[keys[i]], 1u);
    }
  }
  __syncthreads();

  // claim one contiguous run per distinct col (global returning atomic)
  for (int c = tid; c < D_OUT; c += TPB) {
    uint32_t k = lcnt[c];
    lbase[c] = k ? atomicAdd(&cnt[c], k) : 0u;
    lcnt[c] = 0u;                       // reuse as rank counter
  }
  __syncthreads();

#pragma unroll
  for (int i = 0; i < PPT; i++) {
    if (keys[i] >= 0) {
      uint32_t rank = atomicAdd(&lcnt[keys[i]], 1u);   // LDS returning atomic
      uint32_t slot = lbase[keys[i]] + rank;
      if (slot < CAP)
        bins[(size_t)keys[i] * CAP + slot] = make_uint2(exs[i], eys[i]);
    }
  }
}

// ---------------------------------------------------------------------------
// K3: one column per wave (4 cols/block), lane = b. Entries contiguous.
// Pipeline per 8-chunk: [prefetched entries] -> batch 8 xB gathers -> FMA,
// while prefetching the NEXT chunk's entries (overlaps FMA with loads).
// ---------------------------------------------------------------------------
__global__ __launch_bounds__(256) void accum_kernel(
    const uint32_t* __restrict__ cnt, const uint2* __restrict__ bins,
    const uint32_t* __restrict__ xB, float* __restrict__ out) {
  const int lane = threadIdx.x & 63;
  const int wv   = threadIdx.x >> 6;
  const int col  = blockIdx.x * 4 + wv;

  int n = (int)cnt[col];
  n = n < CAP ? n : CAP;
  const uint2* __restrict__ run = bins + (size_t)col * CAP;

  float acc_t = 0.f, acc_n = 0.f;

#define FMA_STAGE(Q, PB)                                                  \
  {                                                                       \
    uint32_t ex_ = (Q).x, ey_ = (Q).y;                                    \
    int rint = (int)((ex_ >> 12) & 1u);                                   \
    float wfr = __half2float(__ushort_as_half((ushort)(ex_ >> 16)));      \
    float xf = __uint_as_float((PB) << 16);                               \
    float xn = __uint_as_float((PB) & 0xffff0000u);                       \
    float xc  = rint ? xf : xn;                                           \
    float wcr = rint ? 1.0f : 1.0f - wfr;                                 \
    float w_t = __half2float(__ushort_as_half((ushort)(ey_ & 0xffffu)));  \
    float w_n = __half2float(__ushort_as_half((ushort)(ey_ >> 16)));      \
    float term = fmaf(wfr, xf, wcr * xc);                                 \
    acc_t = fmaf(w_t, term, acc_t);                                       \
    acc_n = fmaf(w_n, term, acc_n);                                       \
  }

  uint2 q[8], qn[8];
  int e = 0;
  const int nfull = n & ~7;

  if (nfull > 0) {
#pragma unroll
    for (int t = 0; t < 8; t++) q[t] = run[t];          // prologue entries
  }
  for (; e < nfull; ) {
    uint32_t pb[8];
#pragma unroll
    for (int t = 0; t < 8; t++)                         // batch 8 gathers
      pb[t] = xB[(size_t)(q[t].x & 0xfffu) * BB + lane];
    const int enext = e + 8;
    if (enext < nfull) {
#pragma unroll
      for (int t = 0; t < 8; t++) qn[t] = run[enext + t];  // prefetch next
    }
#pragma unroll
    for (int t = 0; t < 8; t++) FMA_STAGE(q[t], pb[t]); // compute (loads fly)
#pragma unroll
    for (int t = 0; t < 8; t++) q[t] = qn[t];
    e = enext;
  }
  for (; e < n; e++) {
    uint2 qq = run[e];
    uint32_t pb = xB[(size_t)(qq.x & 0xfffu) * BB + lane];
    FMA_STAGE(qq, pb)
  }
#undef FMA_STAGE

  atomicAdd(&out[(size_t)col * BB + lane], acc_t);
  if (col + 1 < D_OUT) atomicAdd(&out[(size_t)(col + 1) * BB + lane], acc_n);
}

// ---------------------------------------------------------------------------
// Fallback (ws too small / N too big): direct atomic scatter into out (f32).
// ---------------------------------------------------------------------------
__global__ __launch_bounds__(256) void direct_kernel(
    const float2* __restrict__ ind, const float* __restrict__ val,
    const float* __restrict__ x, float* __restrict__ out, int n) {
  int p = blockIdx.x * 4 + (threadIdx.x >> 6);
  if (p >= n) return;
  int lane = threadIdx.x & 63;
  float2 rc = ind[p];
  float v = val[p];
  float flr = floorf(rc.x), cer = ceilf(rc.x);
  float flc = floorf(rc.y), cec = ceilf(rc.y);
  float wfr = 1.0f - (rc.x - flr);
  float wcr = 1.0f - (cer - rc.x);
  float wfc = 1.0f - (rc.y - flc);
  float wcc = 1.0f - (cec - rc.y);
  float xf = x[(size_t)((int)flr) * BB + lane];
  float xc = x[(size_t)((int)cer) * BB + lane];
  float inner = fmaf(wfr, xf, wcr * xc);
  atomicAdd(&out[(size_t)((int)flc) * BB + lane], v * wfc * inner);
  atomicAdd(&out[(size_t)((int)cec) * BB + lane], v * wcc * inner);
}

// ---------------------------------------------------------------------------
extern "C" void kernel_launch(void* const* d_in, const int* in_sizes, int n_in,
                              void* d_out, int out_size, void* d_ws, size_t ws_size,
                              hipStream_t stream) {
  const float2* ind = (const float2*)d_in[0];   // [N,2] f32
  const float*  val = (const float*)d_in[1];    // [N]   f32
  const float*  x   = (const float*)d_in[2];    // [D_IN*B] f32
  float* out = (float*)d_out;                   // [D_OUT*B] f32
  const int N = in_sizes[1];

  const size_t cnt_bytes = (size_t)D_OUT * sizeof(uint32_t);        // 16 KB
  const size_t bin_bytes = (size_t)D_OUT * CAP * sizeof(uint2);     // 4 MB
  const size_t xb_bytes  = (size_t)D_IN * BB * sizeof(uint32_t);    // 1 MB

  if (N <= NBINB * TPB * PPT &&
      ws_size >= cnt_bytes + bin_bytes + xb_bytes) {
    char* w = (char*)d_ws;
    uint32_t* cnt  = (uint32_t*)w;   w += cnt_bytes;
    uint2*    bins = (uint2*)w;      w += bin_bytes;
    uint32_t* xB   = (uint32_t*)w;

    prep_kernel<<<(D_IN * BB) / 256, 256, 0, stream>>>(x, cnt, out, xB);
    bin_kernel<<<NBINB, TPB, 0, stream>>>(ind, val, cnt, bins, N);
    accum_kernel<<<D_OUT / 4, 256, 0, stream>>>(cnt, bins, xB, out);
  } else {
    (void)hipMemsetAsync(out, 0, (size_t)out_size * sizeof(float), stream);
    direct_kernel<<<(N + 3) / 4, 256, 0, stream>>>(ind, val, x, out, N);
  }
}